// Round 11
// baseline (446.497 us; speedup 1.0000x reference)
//
#include <hip/hip_runtime.h>
#include <math.h>

#define D_MODEL 1024
#define N_HEADS 16
#define D_HEAD  64
#define SEQ     2048
#define BATCH   2
#define M_TOT   (BATCH*SEQ)   // 4096
#define FFN_DIM 4096

typedef __attribute__((ext_vector_type(8))) short bf16x8;   // 8 bf16 = 4 VGPRs
typedef __attribute__((ext_vector_type(4))) float f32x4;
typedef __attribute__((ext_vector_type(8))) unsigned short u16x8;

__device__ __forceinline__ unsigned short f2bf(float f) {
  unsigned int u = __float_as_uint(f);
  return (unsigned short)((u + 0x7fffu + ((u >> 16) & 1u)) >> 16);  // RNE
}
__device__ __forceinline__ unsigned short f2bf_trunc(float f) {
  return (unsigned short)(__float_as_uint(f) >> 16);   // P in [0,1]: rel err <2^-8
}
__device__ __forceinline__ float bf2f(unsigned short s) {
  return __uint_as_float(((unsigned int)s) << 16);
}

__device__ __forceinline__ void async_ld16(void* lds, const void* g) {
  __builtin_amdgcn_global_load_lds(
      (const __attribute__((address_space(1))) unsigned int*)g,
      (__attribute__((address_space(3))) unsigned int*)lds, 16, 0, 0);
}

__device__ __forceinline__ float gelu_exact(float x) {
  return 0.5f * x * (1.f + erff(x * 0.70710678118654752f));
}

// ---------------- fp32 -> bf16 convert, all 4 weight tensors in one launch ------
__global__ __launch_bounds__(256) void cvt_all(const float* __restrict__ qkv_w,
    const float* __restrict__ o_w, const float* __restrict__ w1,
    const float* __restrict__ w2, unsigned short* __restrict__ dst) {
  const long MEGc = 1024*1024;
  long i = (long)(blockIdx.x*256 + threadIdx.x)*4;   // [0, 12M)
  const float* src; long off;
  if (i < 3*MEGc)      { src = qkv_w; off = i; }
  else if (i < 4*MEGc) { src = o_w;  off = i - 3*MEGc; }
  else if (i < 8*MEGc) { src = w1;   off = i - 4*MEGc; }
  else                 { src = w2;   off = i - 8*MEGc; }
  float4 v = *(const float4*)(src + off);
  ushort4 o = { f2bf(v.x), f2bf(v.y), f2bf(v.z), f2bf(v.w) };
  *(ushort4*)(dst + i) = o;
}

// ---------------- LayerNorm: one block (256 thr) per row of 1024, bf16 out ------
__global__ __launch_bounds__(256) void ln_kernel(const float* __restrict__ x,
    const float* __restrict__ w, const float* __restrict__ b,
    unsigned short* __restrict__ out) {
  int row = blockIdx.x;
  const float* xr = x + (size_t)row * D_MODEL;
  int c = threadIdx.x * 4;
  float4 v = *(const float4*)(xr + c);
  float s = v.x + v.y + v.z + v.w;
  __shared__ float red[4];
  #pragma unroll
  for (int o = 32; o > 0; o >>= 1) s += __shfl_down(s, o, 64);
  int wave = threadIdx.x >> 6;
  if ((threadIdx.x & 63) == 0) red[wave] = s;
  __syncthreads();
  float mean = (red[0]+red[1]+red[2]+red[3]) * (1.f/D_MODEL);
  __syncthreads();
  float d0 = v.x-mean, d1 = v.y-mean, d2 = v.z-mean, d3 = v.w-mean;
  float s2 = d0*d0 + d1*d1 + d2*d2 + d3*d3;
  #pragma unroll
  for (int o = 32; o > 0; o >>= 1) s2 += __shfl_down(s2, o, 64);
  if ((threadIdx.x & 63) == 0) red[wave] = s2;
  __syncthreads();
  float var = (red[0]+red[1]+red[2]+red[3]) * (1.f/D_MODEL);
  float rs = rsqrtf(var + 1e-5f);
  float4 wv = *(const float4*)(w + c);
  float4 bv = *(const float4*)(b + c);
  ushort4 o = { f2bf(d0*rs*wv.x + bv.x), f2bf(d1*rs*wv.y + bv.y),
                f2bf(d2*rs*wv.z + bv.z), f2bf(d3*rs*wv.w + bv.w) };
  *(ushort4*)(out + (size_t)row*D_MODEL + c) = o;
}

// ---------------- block swizzle: XCD-chunked + 8-row supertile ------------------
__device__ __forceinline__ void swizzle_block(int nbx, int nby, int& bx, int& by) {
  int nb = nbx * nby;
  int bid = blockIdx.y * nbx + blockIdx.x;
  int chunk = nb >> 3;
  int bid2 = (bid & 7) * chunk + (bid >> 3);   // contiguous region per XCD
  const int GM = 8;
  int ngroup = GM * nbx;
  int g = bid2 / ngroup, rem = bid2 % ngroup;
  by = g*GM + (rem % GM);
  bx = rem / GM;
}

// ---------------- MFMA GEMM, barrier-free: C[m,n]=sum_k A[m,k]*Bt[n,k] ----------
// ONE wave per block (64 thr) owning a 64x64 tile. The wave stages its own A/B
// strips into its own double-buffered LDS via global_load_lds and synchronizes
// with a hand-placed `s_waitcnt vmcnt(8)` ONLY — no __syncthreads in the K-loop,
// so the compiler's block-wide vmcnt(0) barrier drain (the m97 plateau) is gone.
// The in-flight prefetch for tile k+1 is never drained; stalls are per-wave and
// hidden by ~10 independent waves/CU.
// XOR-swizzled LDS image keeps fragment ds_read_b128 conflict-free (r10: 0 cnt).
template<int EPI, bool OBF>
__global__ __launch_bounds__(64) void gemm_mfma(
    const unsigned short* __restrict__ A, const unsigned short* __restrict__ Bt,
    float* __restrict__ Cf, unsigned short* __restrict__ Cb,
    const float* __restrict__ bias, const float* __restrict__ res,
    int M, int N, int K) {
  constexpr int BK = 32;
  __shared__ unsigned short Ls[2][4096];    // per-buffer: [A 64x32 ; B 64x32] 8 KB
  int l = threadIdx.x;
  int lg = l >> 4, lm = l & 15;
  int bx, by;
  swizzle_block(N/64, M/64, bx, by);
  int bm = by*64, bn = bx*64;

  f32x4 acc[4][4];
  #pragma unroll
  for (int i = 0; i < 4; ++i)
    #pragma unroll
    for (int j = 0; j < 4; ++j)
      acc[i][j] = (f32x4){0.f, 0.f, 0.f, 0.f};

  // staging: call c covers flat ushorts [c*512,(c+1)*512); lane l fills slot
  // (row = c*16 + l>>2, pos = l&3) holding global k-chunk pos^((row>>1)&3).
  int swz = (l >> 3) & 3;                   // == (row>>1)&3 for this lane
  const unsigned short* gp[8];
  #pragma unroll
  for (int c = 0; c < 8; ++c) {
    int r = c*16 + (l >> 2);                // row in [A;B] stack
    int col = ((l & 3) ^ swz) * 8;
    gp[c] = (r < 64) ? (A  + (size_t)(bm + r)*K + col)
                     : (Bt + (size_t)(bn + (r - 64))*K + col);
  }
  auto stage = [&](int buf, int k0) {
    #pragma unroll
    for (int c = 0; c < 8; ++c)
      async_ld16(&Ls[buf][c*512 + l*8], gp[c] + k0);
  };

  // fragment reads: k-chunk lg of row lm+16i lives at swizzled pos lg^((lm>>1)&3)
  int lgs = lg ^ ((lm >> 1) & 3);
  int aoff = lm*32 + lgs*8;
  int boff = 2048 + lm*32 + lgs*8;

  auto compute = [&](int buf) {
    bf16x8 af[4], bfr[4];
    #pragma unroll
    for (int i = 0; i < 4; ++i) af[i]  = *(const bf16x8*)&Ls[buf][aoff + i*512];
    #pragma unroll
    for (int j = 0; j < 4; ++j)  bfr[j] = *(const bf16x8*)&Ls[buf][boff + j*512];
    #pragma unroll
    for (int i = 0; i < 4; ++i)
      #pragma unroll
      for (int j = 0; j < 4; ++j)
        acc[i][j] = __builtin_amdgcn_mfma_f32_16x16x32_bf16(af[i], bfr[j], acc[i][j], 0, 0, 0);
  };

  stage(0, 0);
  int niter = K / BK;
  for (int kt = 0; kt < niter - 1; ++kt) {
    stage((kt+1) & 1, (kt+1)*BK);               // 8 new calls in flight
    asm volatile("s_waitcnt vmcnt(8)" ::: "memory");  // oldest 8 (tile kt) landed
    compute(kt & 1);
  }
  asm volatile("s_waitcnt vmcnt(0)" ::: "memory");
  compute((niter-1) & 1);

  // epilogue: C/D layout col = lane&15, row = (lane>>4)*4 + reg
  #pragma unroll
  for (int i = 0; i < 4; ++i) {
    #pragma unroll
    for (int j = 0; j < 4; ++j) {
      int col = bn + j*16 + lm;
      #pragma unroll
      for (int r = 0; r < 4; ++r) {
        int row = bm + i*16 + lg*4 + r;
        float v = acc[i][j][r];
        if (EPI == 1) v = gelu_exact(v + bias[col]);
        if (EPI == 2) v += res[(size_t)row*N + col];
        if (EPI == 3) v += bias[col] + res[(size_t)row*N + col];
        if (OBF) Cb[(size_t)row*N + col] = f2bf(v);
        else     Cf[(size_t)row*N + col] = v;
      }
    }
  }
}

// ---------------- V transpose: qkv V-part -> vT[b][h][d][seq] -------------------
__global__ __launch_bounds__(256) void vtrans_kernel(
    const unsigned short* __restrict__ qkvb, unsigned short* __restrict__ vT) {
  __shared__ unsigned short T[64*72];
  int nt = blockIdx.x, h = blockIdx.y, b = blockIdx.z;
  int tid = threadIdx.x;
  const unsigned short* vb = qkvb + (size_t)(b*SEQ)*(3*D_MODEL) + 2*D_MODEL + h*D_HEAD;
  #pragma unroll
  for (int it = 0; it < 2; ++it) {
    int idx = tid + it*256;
    int r = idx >> 3, c8 = (idx & 7)*8;
    *(u16x8*)&T[r*72 + c8] = *(const u16x8*)(vb + (size_t)(nt*64 + r)*(3*D_MODEL) + c8);
  }
  __syncthreads();
  unsigned short* vto = vT + ((size_t)(b*N_HEADS + h)*D_HEAD)*SEQ + nt*64;
  #pragma unroll
  for (int it = 0; it < 2; ++it) {
    int idx = tid + it*256;
    int d = idx >> 3, s8 = (idx & 7)*8;
    u16x8 o;
    #pragma unroll
    for (int i = 0; i < 8; ++i) o[i] = T[(s8+i)*72 + d];
    *(u16x8*)(vto + (size_t)d*SEQ + s8) = o;
  }
}

// ---------------- MFMA flash attention: 64-wide KV steps, paired q-tiles, -------
// ---------------- register prefetch of next K/V tile ----------------------------
#define ATT_PAD 72
__device__ __forceinline__ void attn_step(
    const bf16x8* aq, float* m_i, float* l_i, f32x4* acc_o,
    const unsigned short* __restrict__ Ks, const unsigned short* __restrict__ Vt,
    unsigned short* __restrict__ pw, int lg, int lm, int qoff, bool diag) {
  f32x4 sacc[4];
  #pragma unroll
  for (int j = 0; j < 4; ++j) sacc[j] = (f32x4){0.f, 0.f, 0.f, 0.f};
  #pragma unroll
  for (int s = 0; s < 2; ++s)
    #pragma unroll
    for (int j = 0; j < 4; ++j)
      sacc[j] = __builtin_amdgcn_mfma_f32_16x16x32_bf16(
          aq[s], *(const bf16x8*)&Ks[(j*16+lm)*ATT_PAD + s*32 + lg*8], sacc[j], 0, 0, 0);
  if (diag) {
    #pragma unroll
    for (int j = 0; j < 4; ++j)
      #pragma unroll
      for (int r = 0; r < 4; ++r)
        if (j*16 + lm > qoff + lg*4 + r) sacc[j][r] = -INFINITY;
  }
  float alpha[4];
  #pragma unroll
  for (int r = 0; r < 4; ++r) {
    float rm = fmaxf(fmaxf(sacc[0][r], sacc[1][r]), fmaxf(sacc[2][r], sacc[3][r]));
    #pragma unroll
    for (int o = 1; o < 16; o <<= 1) rm = fmaxf(rm, __shfl_xor(rm, o));
    float mn = fmaxf(m_i[r], rm);
    alpha[r] = __expf(m_i[r] - mn);
    float rsum = 0.f;
    #pragma unroll
    for (int j = 0; j < 4; ++j) {
      float p = __expf(sacc[j][r] - mn);
      sacc[j][r] = p; rsum += p;
    }
    #pragma unroll
    for (int o = 1; o < 16; o <<= 1) rsum += __shfl_xor(rsum, o);
    l_i[r] = l_i[r]*alpha[r] + rsum;
    m_i[r] = mn;
  }
  #pragma unroll
  for (int j = 0; j < 4; ++j)
    #pragma unroll
    for (int r = 0; r < 4; ++r)
      pw[(lg*4 + r)*ATT_PAD + j*16 + lm] = f2bf_trunc(sacc[j][r]);
  #pragma unroll
  for (int j = 0; j < 4; ++j)
    #pragma unroll
    for (int r = 0; r < 4; ++r)
      acc_o[j][r] *= alpha[r];
  #pragma unroll
  for (int s = 0; s < 2; ++s) {
    bf16x8 ap = *(const bf16x8*)&pw[lm*ATT_PAD + s*32 + lg*8];
    #pragma unroll
    for (int j = 0; j < 4; ++j)
      acc_o[j] = __builtin_amdgcn_mfma_f32_16x16x32_bf16(
          ap, *(const bf16x8*)&Vt[(j*16+lm)*ATT_PAD + s*32 + lg*8], acc_o[j], 0, 0, 0);
  }
}

__global__ __launch_bounds__(256) void attn_mfma_kernel(
    const unsigned short* __restrict__ qkvb, const unsigned short* __restrict__ vT,
    unsigned short* __restrict__ out) {
  __shared__ unsigned short Ks[64*ATT_PAD];
  __shared__ unsigned short Vt[64*ATT_PAD];
  __shared__ unsigned short Pw[4][16*ATT_PAD];

  int pr = blockIdx.x, h = blockIdx.y, b = blockIdx.z;
  int qtH = 31 - pr, qtL = pr;
  int tid = threadIdx.x;
  int w = tid >> 6, l = tid & 63;
  int lg = l >> 4, lm = l & 15;

  const size_t rs3 = 3*D_MODEL;
  const unsigned short* qb  = qkvb + (size_t)(b*SEQ)*rs3 + h*D_HEAD;
  const unsigned short* kb  = qb + D_MODEL;
  const unsigned short* vtb = vT + ((size_t)(b*N_HEADS + h)*D_HEAD)*SEQ;

  bf16x8 aqH[2], aqL[2];
  int qrH = qtH*64 + w*16 + lm, qrL = qtL*64 + w*16 + lm;
  #pragma unroll
  for (int s = 0; s < 2; ++s) {
    u16x8 tH = *(const u16x8*)(qb + (size_t)qrH*rs3 + s*32 + lg*8);
    u16x8 tL = *(const u16x8*)(qb + (size_t)qrL*rs3 + s*32 + lg*8);
    bf16x8 rH, rL;
    #pragma unroll
    for (int i = 0; i < 8; ++i) {
      rH[i] = (short)f2bf(bf2f(tH[i]) * 0.125f);
      rL[i] = (short)f2bf(bf2f(tL[i]) * 0.125f);
    }
    aqH[s] = rH; aqL[s] = rL;
  }

  float mH[4], lH[4], mL[4], lL[4];
  f32x4 oH[4], oL[4];
  #pragma unroll
  for (int r = 0; r < 4; ++r) { mH[r] = -INFINITY; lH[r] = 0.f; mL[r] = -INFINITY; lL[r] = 0.f; }
  #pragma unroll
  for (int j = 0; j < 4; ++j) { oH[j] = (f32x4){0.f,0.f,0.f,0.f}; oL[j] = (f32x4){0.f,0.f,0.f,0.f}; }

  unsigned short* pw = &Pw[w][0];

  int sidx0 = tid, sidx1 = tid + 256;
  int sr0 = sidx0 >> 3, sc0 = (sidx0 & 7)*8;
  int sr1 = sidx1 >> 3, sc1 = (sidx1 & 7)*8;

  u16x8 kreg[2], vreg[2];
  auto prefetch = [&](int kt) {
    kreg[0] = *(const u16x8*)(kb  + (size_t)(kt*64 + sr0)*rs3 + sc0);
    kreg[1] = *(const u16x8*)(kb  + (size_t)(kt*64 + sr1)*rs3 + sc1);
    vreg[0] = *(const u16x8*)(vtb + (size_t)sr0*SEQ + kt*64 + sc0);
    vreg[1] = *(const u16x8*)(vtb + (size_t)sr1*SEQ + kt*64 + sc1);
  };

  prefetch(0);
  for (int kt = 0; kt <= qtH; ++kt) {
    __syncthreads();
    *(u16x8*)&Ks[sr0*ATT_PAD + sc0] = kreg[0];
    *(u16x8*)&Ks[sr1*ATT_PAD + sc1] = kreg[1];
    *(u16x8*)&Vt[sr0*ATT_PAD + sc0] = vreg[0];
    *(u16x8*)&Vt[sr1*ATT_PAD + sc1] = vreg[1];
    __syncthreads();
    if (kt < qtH) prefetch(kt+1);
    attn_step(aqH, mH, lH, oH, Ks, Vt, pw, lg, lm, w*16, kt == qtH);
    if (kt <= qtL)
      attn_step(aqL, mL, lL, oL, Ks, Vt, pw, lg, lm, w*16, kt == qtL);
  }

  #pragma unroll
  for (int r = 0; r < 4; ++r) {
    float invH = 1.f / lH[r], invL = 1.f / lL[r];
    int qH = qtH*64 + w*16 + lg*4 + r;
    int qL = qtL*64 + w*16 + lg*4 + r;
    #pragma unroll
    for (int j = 0; j < 4; ++j) {
      out[((size_t)(b*SEQ + qH))*D_MODEL + h*D_HEAD + j*16 + lm] = f2bf(oH[j][r]*invH);
      out[((size_t)(b*SEQ + qL))*D_MODEL + h*D_HEAD + j*16 + lm] = f2bf(oL[j][r]*invL);
    }
  }
}

extern "C" void kernel_launch(void* const* d_in, const int* in_sizes, int n_in,
                              void* d_out, int out_size, void* d_ws, size_t ws_size,
                              hipStream_t stream) {
  const float* x      = (const float*)d_in[0];
  const float* ln1_w  = (const float*)d_in[1];
  const float* ln1_b  = (const float*)d_in[2];
  const float* ln2_w  = (const float*)d_in[3];
  const float* ln2_b  = (const float*)d_in[4];
  const float* qkv_w  = (const float*)d_in[5];
  const float* o_w    = (const float*)d_in[6];
  const float* ffn_w1 = (const float*)d_in[7];
  const float* ffn_b1 = (const float*)d_in[8];
  const float* ffn_w2 = (const float*)d_in[9];
  const float* ffn_b2 = (const float*)d_in[10];
  float* out = (float*)d_out;
  float* ws  = (float*)d_ws;

  const size_t MEG = 1024*1024;
  unsigned short* wqkv = (unsigned short*)ws;              // 3M shorts
  unsigned short* wo   = wqkv + 3*MEG;                     // 1M
  unsigned short* w1   = wo   + 1*MEG;                     // 4M
  unsigned short* w2   = w1   + 4*MEG;                     // 4M
  unsigned short* hbf    = (unsigned short*)(ws + 6*MEG);  // [6M,8M)  h / h2
  unsigned short* attnbf = (unsigned short*)(ws + 8*MEG);  // [8M,10M)
  float* x1  = ws + 10*MEG;                                // [10M,14M)
  unsigned short* qkvb = (unsigned short*)(ws + 14*MEG);   // [14M,20M) dead after attn
  unsigned short* ffbf = (unsigned short*)(ws + 14*MEG);   // [14M,22M) reuses qkvb
  unsigned short* vT   = (unsigned short*)(ws + 22*MEG);   // [22M,24M)

  // 0. weights -> bf16 (single launch)
  cvt_all<<<12*MEG/1024, 256, 0, stream>>>(qkv_w, o_w, ffn_w1, ffn_w2, wqkv);
  // 1. h = LN1(x) -> bf16
  ln_kernel<<<M_TOT, 256, 0, stream>>>(x, ln1_w, ln1_b, hbf);
  // 2. qkv = h @ qkv_w.T  (4096 x 3072 x 1024) -> bf16
  gemm_mfma<0,true><<<dim3(3*D_MODEL/64, M_TOT/64), 64, 0, stream>>>(
      hbf, wqkv, nullptr, qkvb, nullptr, nullptr, M_TOT, 3*D_MODEL, D_MODEL);
  // 2.5 vT = transpose(V)
  vtrans_kernel<<<dim3(SEQ/64, N_HEADS, BATCH), 256, 0, stream>>>(qkvb, vT);
  // 3. attn = causal MHA -> bf16, paired-tile MFMA flash + reg prefetch
  attn_mfma_kernel<<<dim3(16, N_HEADS, BATCH), 256, 0, stream>>>(qkvb, vT, attnbf);
  // 4. x1 = x + attn @ o_w.T  (4096 x 1024 x 1024) -> fp32
  gemm_mfma<2,false><<<dim3(D_MODEL/64, M_TOT/64), 64, 0, stream>>>(
      attnbf, wo, x1, nullptr, nullptr, x, M_TOT, D_MODEL, D_MODEL);
  // 5. h2 = LN2(x1) -> bf16
  ln_kernel<<<M_TOT, 256, 0, stream>>>(x1, ln2_w, ln2_b, hbf);
  // 6. ff = gelu(h2 @ ffn_w1.T + b1)  (4096 x 4096 x 1024) -> bf16
  gemm_mfma<1,true><<<dim3(FFN_DIM/64, M_TOT/64), 64, 0, stream>>>(
      hbf, w1, nullptr, ffbf, ffn_b1, nullptr, M_TOT, FFN_DIM, D_MODEL);
  // 7. out = x1 + ff @ ffn_w2.T + b2  (4096 x 1024 x 4096) -> fp32
  gemm_mfma<3,false><<<dim3(D_MODEL/64, M_TOT/64), 64, 0, stream>>>(
      ffbf, w2, out, nullptr, ffn_b2, x1, M_TOT, D_MODEL, FFN_DIM);
}

// Round 12
// 377.177 us; speedup vs baseline: 1.1838x; 1.1838x over previous
//
#include <hip/hip_runtime.h>
#include <math.h>

#define D_MODEL 1024
#define N_HEADS 16
#define D_HEAD  64
#define SEQ     2048
#define BATCH   2
#define M_TOT   (BATCH*SEQ)   // 4096
#define FFN_DIM 4096

typedef __attribute__((ext_vector_type(8))) short bf16x8;   // 8 bf16 = 4 VGPRs
typedef __attribute__((ext_vector_type(4))) float f32x4;
typedef __attribute__((ext_vector_type(8))) unsigned short u16x8;

__device__ __forceinline__ unsigned short f2bf(float f) {
  unsigned int u = __float_as_uint(f);
  return (unsigned short)((u + 0x7fffu + ((u >> 16) & 1u)) >> 16);  // RNE
}
__device__ __forceinline__ unsigned short f2bf_trunc(float f) {
  return (unsigned short)(__float_as_uint(f) >> 16);   // P in [0,1]: rel err <2^-8
}
__device__ __forceinline__ float bf2f(unsigned short s) {
  return __uint_as_float(((unsigned int)s) << 16);
}

__device__ __forceinline__ float gelu_exact(float x) {
  return 0.5f * x * (1.f + erff(x * 0.70710678118654752f));
}

// ---------------- fp32 -> bf16 convert, all 4 weight tensors in one launch ------
__global__ __launch_bounds__(256) void cvt_all(const float* __restrict__ qkv_w,
    const float* __restrict__ o_w, const float* __restrict__ w1,
    const float* __restrict__ w2, unsigned short* __restrict__ dst) {
  const long MEGc = 1024*1024;
  long i = (long)(blockIdx.x*256 + threadIdx.x)*4;   // [0, 12M)
  const float* src; long off;
  if (i < 3*MEGc)      { src = qkv_w; off = i; }
  else if (i < 4*MEGc) { src = o_w;  off = i - 3*MEGc; }
  else if (i < 8*MEGc) { src = w1;   off = i - 4*MEGc; }
  else                 { src = w2;   off = i - 8*MEGc; }
  float4 v = *(const float4*)(src + off);
  ushort4 o = { f2bf(v.x), f2bf(v.y), f2bf(v.z), f2bf(v.w) };
  *(ushort4*)(dst + i) = o;
}

// ---------------- LayerNorm: one block (256 thr) per row of 1024, bf16 out ------
__global__ __launch_bounds__(256) void ln_kernel(const float* __restrict__ x,
    const float* __restrict__ w, const float* __restrict__ b,
    unsigned short* __restrict__ out) {
  int row = blockIdx.x;
  const float* xr = x + (size_t)row * D_MODEL;
  int c = threadIdx.x * 4;
  float4 v = *(const float4*)(xr + c);
  float s = v.x + v.y + v.z + v.w;
  __shared__ float red[4];
  #pragma unroll
  for (int o = 32; o > 0; o >>= 1) s += __shfl_down(s, o, 64);
  int wave = threadIdx.x >> 6;
  if ((threadIdx.x & 63) == 0) red[wave] = s;
  __syncthreads();
  float mean = (red[0]+red[1]+red[2]+red[3]) * (1.f/D_MODEL);
  __syncthreads();
  float d0 = v.x-mean, d1 = v.y-mean, d2 = v.z-mean, d3 = v.w-mean;
  float s2 = d0*d0 + d1*d1 + d2*d2 + d3*d3;
  #pragma unroll
  for (int o = 32; o > 0; o >>= 1) s2 += __shfl_down(s2, o, 64);
  if ((threadIdx.x & 63) == 0) red[wave] = s2;
  __syncthreads();
  float var = (red[0]+red[1]+red[2]+red[3]) * (1.f/D_MODEL);
  float rs = rsqrtf(var + 1e-5f);
  float4 wv = *(const float4*)(w + c);
  float4 bv = *(const float4*)(b + c);
  ushort4 o = { f2bf(d0*rs*wv.x + bv.x), f2bf(d1*rs*wv.y + bv.y),
                f2bf(d2*rs*wv.z + bv.z), f2bf(d3*rs*wv.w + bv.w) };
  *(ushort4*)(out + (size_t)row*D_MODEL + c) = o;
}

// ---------------- block swizzle: XCD-chunked + 8-row supertile ------------------
__device__ __forceinline__ void swizzle_block(int nbx, int nby, int& bx, int& by) {
  int nb = nbx * nby;
  int bid = blockIdx.y * nbx + blockIdx.x;
  int chunk = nb >> 3;
  int bid2 = (bid & 7) * chunk + (bid >> 3);   // contiguous region per XCD
  const int GM = 8;
  int ngroup = GM * nbx;
  int g = bid2 / ngroup, rem = bid2 % ngroup;
  by = g*GM + (rem % GM);
  bx = rem / GM;
}

// ---------------- MFMA GEMM, register-staged pipeline ---------------------------
// 4-wave (256-thr) blocks, BM=128, BK=32. Staging = global_load -> VGPR ->
// ds_write (NOT global_load_lds): the compiler then uses per-load vmcnt AFTER
// the compute leg instead of draining vmcnt(0) at every barrier (the r8-r11
// plateau; glld->LDS deps force a full drain before dependent ds_read — m131).
// One __syncthreads per K-iter; writes go to the other LDS buffer (race-free).
// XOR-swizzled LDS image keeps fragment ds_read_b128 conflict-free (r10: 0 cnt).
// BN=128: waves 2x2, each 64x64 (4x4 frags). BN=64: each wave 64x32 (4x2).
template<int EPI, bool OBF, int BN>
__global__ __launch_bounds__(256) void gemm_mfma(
    const unsigned short* __restrict__ A, const unsigned short* __restrict__ Bt,
    float* __restrict__ Cf, unsigned short* __restrict__ Cb,
    const float* __restrict__ bias, const float* __restrict__ res,
    int M, int N, int K) {
  constexpr int BM = 128, BK = 32;
  constexpr int TS = (BM + BN) * BK;        // ushorts per staged [A;B] stack
  constexpr int CPT = TS / 2048;            // 16B chunks per thread (4 or 3)
  constexpr int NI = (BN == 128) ? 4 : 2;
  __shared__ unsigned short Ls[2][TS];
  int tid = threadIdx.x;
  int w = tid >> 6, l = tid & 63;
  int lg = l >> 4, lm = l & 15;
  int bx, by;
  swizzle_block(N/BN, M/BM, bx, by);
  int bm = by * BM, bn = bx * BN;
  int wm = (w >> 1) * 64;
  int wn = (w & 1) * (BN/2);

  f32x4 acc[4][NI];
  #pragma unroll
  for (int i = 0; i < 4; ++i)
    #pragma unroll
    for (int j = 0; j < NI; ++j)
      acc[i][j] = (f32x4){0.f, 0.f, 0.f, 0.f};

  // staging map: flat chunk fc = i*256 + tid; row = fc>>2 (32 ushorts/row),
  // slot pos = fc&3; slot holds global k-chunk pos^swz, swz = (row>>1)&3.
  const unsigned short* gp[CPT];
  int lo[CPT];
  #pragma unroll
  for (int i = 0; i < CPT; ++i) {
    int fc = i*256 + tid;
    int r = fc >> 2;
    int swz = (fc >> 3) & 3;
    int col = ((fc & 3) ^ swz) * 8;
    lo[i] = fc * 8;
    gp[i] = (r < BM) ? (A  + (size_t)(bm + r)*K + col)
                     : (Bt + (size_t)(bn + (r - BM))*K + col);
  }
  u16x8 sreg[CPT];
  auto loadregs = [&](int k0) {
    #pragma unroll
    for (int i = 0; i < CPT; ++i) sreg[i] = *(const u16x8*)(gp[i] + k0);
  };
  auto dswrite = [&](int buf) {
    #pragma unroll
    for (int i = 0; i < CPT; ++i) *(u16x8*)&Ls[buf][lo[i]] = sreg[i];
  };

  // fragment reads: k-chunk lg of row (wm/wn+lm+16i) at swizzled pos lg^((lm>>1)&3)
  int lgs = lg ^ ((lm >> 1) & 3);
  int aoff = (wm + lm)*BK + lgs*8;
  int boff = BM*BK + (wn + lm)*BK + lgs*8;

  auto compute = [&](int buf) {
    bf16x8 af[4], bfr[NI];
    #pragma unroll
    for (int i = 0; i < 4; ++i)  af[i]  = *(const bf16x8*)&Ls[buf][aoff + i*512];
    #pragma unroll
    for (int j = 0; j < NI; ++j) bfr[j] = *(const bf16x8*)&Ls[buf][boff + j*512];
    #pragma unroll
    for (int i = 0; i < 4; ++i)
      #pragma unroll
      for (int j = 0; j < NI; ++j)
        acc[i][j] = __builtin_amdgcn_mfma_f32_16x16x32_bf16(af[i], bfr[j], acc[i][j], 0, 0, 0);
  };

  loadregs(0);
  dswrite(0);
  __syncthreads();
  int niter = K / BK;
  for (int kt = 0; kt < niter; ++kt) {
    if (kt + 1 < niter) loadregs((kt+1)*BK);   // latency overlaps compute below
    compute(kt & 1);
    if (kt + 1 < niter) {
      dswrite((kt+1) & 1);                     // other buffer: race-free pre-barrier
      __syncthreads();                         // lgkm-only barrier, no vmem drain
    }
  }

  // epilogue: C/D layout col = lane&15, row = (lane>>4)*4 + reg
  #pragma unroll
  for (int i = 0; i < 4; ++i) {
    #pragma unroll
    for (int j = 0; j < NI; ++j) {
      int col = bn + wn + j*16 + lm;
      #pragma unroll
      for (int r = 0; r < 4; ++r) {
        int row = bm + wm + i*16 + lg*4 + r;
        float v = acc[i][j][r];
        if (EPI == 1) v = gelu_exact(v + bias[col]);
        if (EPI == 2) v += res[(size_t)row*N + col];
        if (EPI == 3) v += bias[col] + res[(size_t)row*N + col];
        if (OBF) Cb[(size_t)row*N + col] = f2bf(v);
        else     Cf[(size_t)row*N + col] = v;
      }
    }
  }
}

// ---------------- V transpose: qkv V-part -> vT[b][h][d][seq] -------------------
__global__ __launch_bounds__(256) void vtrans_kernel(
    const unsigned short* __restrict__ qkvb, unsigned short* __restrict__ vT) {
  __shared__ unsigned short T[64*72];
  int nt = blockIdx.x, h = blockIdx.y, b = blockIdx.z;
  int tid = threadIdx.x;
  const unsigned short* vb = qkvb + (size_t)(b*SEQ)*(3*D_MODEL) + 2*D_MODEL + h*D_HEAD;
  #pragma unroll
  for (int it = 0; it < 2; ++it) {
    int idx = tid + it*256;
    int r = idx >> 3, c8 = (idx & 7)*8;
    *(u16x8*)&T[r*72 + c8] = *(const u16x8*)(vb + (size_t)(nt*64 + r)*(3*D_MODEL) + c8);
  }
  __syncthreads();
  unsigned short* vto = vT + ((size_t)(b*N_HEADS + h)*D_HEAD)*SEQ + nt*64;
  #pragma unroll
  for (int it = 0; it < 2; ++it) {
    int idx = tid + it*256;
    int d = idx >> 3, s8 = (idx & 7)*8;
    u16x8 o;
    #pragma unroll
    for (int i = 0; i < 8; ++i) o[i] = T[(s8+i)*72 + d];
    *(u16x8*)(vto + (size_t)d*SEQ + s8) = o;
  }
}

// ---------------- MFMA flash attention: 64-wide KV steps, paired q-tiles, -------
// ---------------- register prefetch of next K/V tile ----------------------------
#define ATT_PAD 72
__device__ __forceinline__ void attn_step(
    const bf16x8* aq, float* m_i, float* l_i, f32x4* acc_o,
    const unsigned short* __restrict__ Ks, const unsigned short* __restrict__ Vt,
    unsigned short* __restrict__ pw, int lg, int lm, int qoff, bool diag) {
  f32x4 sacc[4];
  #pragma unroll
  for (int j = 0; j < 4; ++j) sacc[j] = (f32x4){0.f, 0.f, 0.f, 0.f};
  #pragma unroll
  for (int s = 0; s < 2; ++s)
    #pragma unroll
    for (int j = 0; j < 4; ++j)
      sacc[j] = __builtin_amdgcn_mfma_f32_16x16x32_bf16(
          aq[s], *(const bf16x8*)&Ks[(j*16+lm)*ATT_PAD + s*32 + lg*8], sacc[j], 0, 0, 0);
  if (diag) {
    #pragma unroll
    for (int j = 0; j < 4; ++j)
      #pragma unroll
      for (int r = 0; r < 4; ++r)
        if (j*16 + lm > qoff + lg*4 + r) sacc[j][r] = -INFINITY;
  }
  float alpha[4];
  #pragma unroll
  for (int r = 0; r < 4; ++r) {
    float rm = fmaxf(fmaxf(sacc[0][r], sacc[1][r]), fmaxf(sacc[2][r], sacc[3][r]));
    #pragma unroll
    for (int o = 1; o < 16; o <<= 1) rm = fmaxf(rm, __shfl_xor(rm, o));
    float mn = fmaxf(m_i[r], rm);
    alpha[r] = __expf(m_i[r] - mn);
    float rsum = 0.f;
    #pragma unroll
    for (int j = 0; j < 4; ++j) {
      float p = __expf(sacc[j][r] - mn);
      sacc[j][r] = p; rsum += p;
    }
    #pragma unroll
    for (int o = 1; o < 16; o <<= 1) rsum += __shfl_xor(rsum, o);
    l_i[r] = l_i[r]*alpha[r] + rsum;
    m_i[r] = mn;
  }
  #pragma unroll
  for (int j = 0; j < 4; ++j)
    #pragma unroll
    for (int r = 0; r < 4; ++r)
      pw[(lg*4 + r)*ATT_PAD + j*16 + lm] = f2bf_trunc(sacc[j][r]);
  #pragma unroll
  for (int j = 0; j < 4; ++j)
    #pragma unroll
    for (int r = 0; r < 4; ++r)
      acc_o[j][r] *= alpha[r];
  #pragma unroll
  for (int s = 0; s < 2; ++s) {
    bf16x8 ap = *(const bf16x8*)&pw[lm*ATT_PAD + s*32 + lg*8];
    #pragma unroll
    for (int j = 0; j < 4; ++j)
      acc_o[j] = __builtin_amdgcn_mfma_f32_16x16x32_bf16(
          ap, *(const bf16x8*)&Vt[(j*16+lm)*ATT_PAD + s*32 + lg*8], acc_o[j], 0, 0, 0);
  }
}

__global__ __launch_bounds__(256) void attn_mfma_kernel(
    const unsigned short* __restrict__ qkvb, const unsigned short* __restrict__ vT,
    unsigned short* __restrict__ out) {
  __shared__ unsigned short Ks[64*ATT_PAD];
  __shared__ unsigned short Vt[64*ATT_PAD];
  __shared__ unsigned short Pw[4][16*ATT_PAD];

  int pr = blockIdx.x, h = blockIdx.y, b = blockIdx.z;
  int qtH = 31 - pr, qtL = pr;
  int tid = threadIdx.x;
  int w = tid >> 6, l = tid & 63;
  int lg = l >> 4, lm = l & 15;

  const size_t rs3 = 3*D_MODEL;
  const unsigned short* qb  = qkvb + (size_t)(b*SEQ)*rs3 + h*D_HEAD;
  const unsigned short* kb  = qb + D_MODEL;
  const unsigned short* vtb = vT + ((size_t)(b*N_HEADS + h)*D_HEAD)*SEQ;

  bf16x8 aqH[2], aqL[2];
  int qrH = qtH*64 + w*16 + lm, qrL = qtL*64 + w*16 + lm;
  #pragma unroll
  for (int s = 0; s < 2; ++s) {
    u16x8 tH = *(const u16x8*)(qb + (size_t)qrH*rs3 + s*32 + lg*8);
    u16x8 tL = *(const u16x8*)(qb + (size_t)qrL*rs3 + s*32 + lg*8);
    bf16x8 rH, rL;
    #pragma unroll
    for (int i = 0; i < 8; ++i) {
      rH[i] = (short)f2bf(bf2f(tH[i]) * 0.125f);
      rL[i] = (short)f2bf(bf2f(tL[i]) * 0.125f);
    }
    aqH[s] = rH; aqL[s] = rL;
  }

  float mH[4], lH[4], mL[4], lL[4];
  f32x4 oH[4], oL[4];
  #pragma unroll
  for (int r = 0; r < 4; ++r) { mH[r] = -INFINITY; lH[r] = 0.f; mL[r] = -INFINITY; lL[r] = 0.f; }
  #pragma unroll
  for (int j = 0; j < 4; ++j) { oH[j] = (f32x4){0.f,0.f,0.f,0.f}; oL[j] = (f32x4){0.f,0.f,0.f,0.f}; }

  unsigned short* pw = &Pw[w][0];

  int sidx0 = tid, sidx1 = tid + 256;
  int sr0 = sidx0 >> 3, sc0 = (sidx0 & 7)*8;
  int sr1 = sidx1 >> 3, sc1 = (sidx1 & 7)*8;

  u16x8 kreg[2], vreg[2];
  auto prefetch = [&](int kt) {
    kreg[0] = *(const u16x8*)(kb  + (size_t)(kt*64 + sr0)*rs3 + sc0);
    kreg[1] = *(const u16x8*)(kb  + (size_t)(kt*64 + sr1)*rs3 + sc1);
    vreg[0] = *(const u16x8*)(vtb + (size_t)sr0*SEQ + kt*64 + sc0);
    vreg[1] = *(const u16x8*)(vtb + (size_t)sr1*SEQ + kt*64 + sc1);
  };

  prefetch(0);
  for (int kt = 0; kt <= qtH; ++kt) {
    __syncthreads();
    *(u16x8*)&Ks[sr0*ATT_PAD + sc0] = kreg[0];
    *(u16x8*)&Ks[sr1*ATT_PAD + sc1] = kreg[1];
    *(u16x8*)&Vt[sr0*ATT_PAD + sc0] = vreg[0];
    *(u16x8*)&Vt[sr1*ATT_PAD + sc1] = vreg[1];
    __syncthreads();
    if (kt < qtH) prefetch(kt+1);
    attn_step(aqH, mH, lH, oH, Ks, Vt, pw, lg, lm, w*16, kt == qtH);
    if (kt <= qtL)
      attn_step(aqL, mL, lL, oL, Ks, Vt, pw, lg, lm, w*16, kt == qtL);
  }

  #pragma unroll
  for (int r = 0; r < 4; ++r) {
    float invH = 1.f / lH[r], invL = 1.f / lL[r];
    int qH = qtH*64 + w*16 + lg*4 + r;
    int qL = qtL*64 + w*16 + lg*4 + r;
    #pragma unroll
    for (int j = 0; j < 4; ++j) {
      out[((size_t)(b*SEQ + qH))*D_MODEL + h*D_HEAD + j*16 + lm] = f2bf(oH[j][r]*invH);
      out[((size_t)(b*SEQ + qL))*D_MODEL + h*D_HEAD + j*16 + lm] = f2bf(oL[j][r]*invL);
    }
  }
}

extern "C" void kernel_launch(void* const* d_in, const int* in_sizes, int n_in,
                              void* d_out, int out_size, void* d_ws, size_t ws_size,
                              hipStream_t stream) {
  const float* x      = (const float*)d_in[0];
  const float* ln1_w  = (const float*)d_in[1];
  const float* ln1_b  = (const float*)d_in[2];
  const float* ln2_w  = (const float*)d_in[3];
  const float* ln2_b  = (const float*)d_in[4];
  const float* qkv_w  = (const float*)d_in[5];
  const float* o_w    = (const float*)d_in[6];
  const float* ffn_w1 = (const float*)d_in[7];
  const float* ffn_b1 = (const float*)d_in[8];
  const float* ffn_w2 = (const float*)d_in[9];
  const float* ffn_b2 = (const float*)d_in[10];
  float* out = (float*)d_out;
  float* ws  = (float*)d_ws;

  const size_t MEG = 1024*1024;
  unsigned short* wqkv = (unsigned short*)ws;              // 3M shorts
  unsigned short* wo   = wqkv + 3*MEG;                     // 1M
  unsigned short* w1   = wo   + 1*MEG;                     // 4M
  unsigned short* w2   = w1   + 4*MEG;                     // 4M
  unsigned short* hbf    = (unsigned short*)(ws + 6*MEG);  // [6M,8M)  h / h2
  unsigned short* attnbf = (unsigned short*)(ws + 8*MEG);  // [8M,10M)
  float* x1  = ws + 10*MEG;                                // [10M,14M)
  unsigned short* qkvb = (unsigned short*)(ws + 14*MEG);   // [14M,20M) dead after attn
  unsigned short* ffbf = (unsigned short*)(ws + 14*MEG);   // [14M,22M) reuses qkvb
  unsigned short* vT   = (unsigned short*)(ws + 22*MEG);   // [22M,24M)

  // 0. weights -> bf16 (single launch)
  cvt_all<<<12*MEG/1024, 256, 0, stream>>>(qkv_w, o_w, ffn_w1, ffn_w2, wqkv);
  // 1. h = LN1(x) -> bf16
  ln_kernel<<<M_TOT, 256, 0, stream>>>(x, ln1_w, ln1_b, hbf);
  // 2. qkv = h @ qkv_w.T  (4096 x 3072 x 1024) -> bf16, 128x128 tiles
  gemm_mfma<0,true,128><<<dim3(3*D_MODEL/128, M_TOT/128), 256, 0, stream>>>(
      hbf, wqkv, nullptr, qkvb, nullptr, nullptr, M_TOT, 3*D_MODEL, D_MODEL);
  // 2.5 vT = transpose(V)
  vtrans_kernel<<<dim3(SEQ/64, N_HEADS, BATCH), 256, 0, stream>>>(qkvb, vT);
  // 3. attn = causal MHA -> bf16, paired-tile MFMA flash + reg prefetch
  attn_mfma_kernel<<<dim3(16, N_HEADS, BATCH), 256, 0, stream>>>(qkvb, vT, attnbf);
  // 4. x1 = x + attn @ o_w.T  (4096 x 1024 x 1024) -> fp32, 128x64 tiles
  gemm_mfma<2,false,64><<<dim3(D_MODEL/64, M_TOT/128), 256, 0, stream>>>(
      attnbf, wo, x1, nullptr, nullptr, x, M_TOT, D_MODEL, D_MODEL);
  // 5. h2 = LN2(x1) -> bf16
  ln_kernel<<<M_TOT, 256, 0, stream>>>(x1, ln2_w, ln2_b, hbf);
  // 6. ff = gelu(h2 @ ffn_w1.T + b1)  (4096 x 4096 x 1024) -> bf16, 128x128 tiles
  gemm_mfma<1,true,128><<<dim3(FFN_DIM/128, M_TOT/128), 256, 0, stream>>>(
      hbf, w1, nullptr, ffbf, ffn_b1, nullptr, M_TOT, FFN_DIM, D_MODEL);
  // 7. out = x1 + ff @ ffn_w2.T + b2  (4096 x 1024 x 4096) -> fp32, 128x64 tiles
  gemm_mfma<3,false,64><<<dim3(D_MODEL/64, M_TOT/128), 256, 0, stream>>>(
      ffbf, w2, out, nullptr, ffn_b2, x1, M_TOT, D_MODEL, FFN_DIM);
}